// Round 10
// baseline (39.653 us; speedup 1.0000x reference)
//
#include <hip/hip_runtime.h>
#include <math.h>

#define LAT_CONST  ((float)(5.0 * 0.03 / 200.0 + 0.06))   // 0.06075
#define GRAD_CONST ((float)(1.0 / 0.06))                  // 16.666666...
#define SEND_CONST ((float)(2.0 / 3.0))                   // 0.666666...

// Wide table (step 1, gathered from global/L2 as f32): t = x2_init*f in [-24,24].
#define NW   2048
#define LOW_ (-24.f)
#define HIW_ (24.f)
#define HW_  ((HIW_ - LOW_) / (float)NW)
#define IHW_ ((float)NW / (HIW_ - LOW_))
#define CW_  (-LOW_ * IHW_)
// Narrow table (steps 2..10, LDS bf16-pair packed): x2 in (0,1), f in (-5.8, 1].
#define N2   2048
#define LO2  (-6.25f)
#define HI2  (1.25f)
#define H2   ((HI2 - LO2) / (float)N2)
#define IH2  ((float)N2 / (HI2 - LO2))
#define C2   (-LO2 * IH2)

#define GSZ   2080      // f32 entries built per table in ws (padded)
#define GPCK  2064      // packed u32 narrow entries in LDS (gathers use <= N2+1)

// ---------------- Kernel 1: build both f32 tables ----------------
// 64 entries/block, layer-2 j-split across the block's 4 waves.
__global__ __launch_bounds__(256)
void build_table_kernel(const float* __restrict__ W1, const float* __restrict__ b1,
                        const float* __restrict__ W2, const float* __restrict__ b2,
                        const float* __restrict__ W3, const float* __restrict__ b3,
                        float* __restrict__ g1, float* __restrict__ g2)
{
    __shared__ float pl[4][64];

    const int lane = threadIdx.x & 63;
    const int w    = threadIdx.x >> 6;
    const int i    = blockIdx.x * 64 + lane;          // 0 .. 2*GSZ-1

    float t;
    if (i < GSZ) t = LOW_ + (float)i * HW_;
    else         t = LO2 + (float)(i - GSZ) * H2;

    float x4 = t + LAT_CONST;
    float x5 = t * SEND_CONST;
    float x3 = x4 * GRAD_CONST;

    float h1v[64];
#pragma unroll
    for (int j = 0; j < 64; ++j) {
        float acc = b1[j];
        acc = fmaf(x3, W1[j],       acc);
        acc = fmaf(x4, W1[64 + j],  acc);
        acc = fmaf(x5, W1[128 + j], acc);
        h1v[j] = fmaxf(acc, 0.f);
    }

    const int j0 = w * 16;
    float acc[16];
#pragma unroll
    for (int u = 0; u < 16; ++u) acc[u] = b2[j0 + u];
#pragma unroll
    for (int k = 0; k < 64; ++k) {
        const float* __restrict__ w2r = W2 + k * 64 + j0;
#pragma unroll
        for (int u = 0; u < 16; ++u)
            acc[u] = fmaf(h1v[k], w2r[u], acc[u]);
    }
    float partial = 0.f;
#pragma unroll
    for (int u = 0; u < 16; ++u)
        partial = fmaf(fmaxf(acc[u], 0.f), W3[j0 + u], partial);

    pl[w][lane] = partial;
    __syncthreads();

    if (w == 0) {
        float logit = b3[0] + ((pl[0][lane] + pl[1][lane]) + (pl[2][lane] + pl[3][lane]));
        float g = 1.f / (1.f + expf(-logit));
        if (i < GSZ) g1[i] = g;
        else         g2[i - GSZ] = g;
    }
}

// ---------------- Kernel 2: persistent pipelined row update ----------------
#define CHUNK 256
#define BLOCK 256
#define MAXBLK 1792       // 7 blocks/CU * 256 CU (LDS 22.6 KB -> 7/CU)

typedef unsigned int u32;
typedef __attribute__((address_space(3))) u32 lds_u32_t;
typedef __attribute__((address_space(1))) const u32 glb_u32_t;

__device__ __forceinline__ void gload16(const void* g, void* l) {
    __builtin_amdgcn_global_load_lds((glb_u32_t*)g, (lds_u32_t*)l, 16, 0, 0);
}
__device__ __forceinline__ void gload4(const void* g, void* l) {
    __builtin_amdgcn_global_load_lds((glb_u32_t*)g, (lds_u32_t*)l, 4, 0, 0);
}

__device__ __forceinline__ u32 bfpack(float a, float b) {
    u32 ua = __float_as_uint(a), ub = __float_as_uint(b);
    ua = (ua + 0x7fffu + ((ua >> 16) & 1u)) >> 16;          // RNE to bf16
    ub = (ub + 0x7fffu + ((ub >> 16) & 1u)) & 0xffff0000u;  // RNE, keep high half
    return (ua & 0xffffu) | ub;
}

__device__ __forceinline__ float lerp_pk(u32 u, float fr) {
    float e0 = __uint_as_float(u << 16);
    float e1 = __uint_as_float(u & 0xffff0000u);
    return fmaf(e1 - e0, fr, e0);
}

__global__ __launch_bounds__(BLOCK)
void rows_kernel(const float* __restrict__ x, const float* __restrict__ g1,
                 const float* __restrict__ g2, float* __restrict__ out,
                 int B, int nChunks, int grid)
{
    __shared__ u32 tn[GPCK];                           // 8256 B
    __shared__ __align__(16) float buf[2][CHUNK * 7];  // 14336 B  (total 22592 B)

    const int tid = threadIdx.x;
    const long long b = blockIdx.x;
    const int cb = (int)(b * (long long)nChunks / grid);
    const int ce = (int)((b + 1) * (long long)nChunks / grid);

    // Prologue: async-DMA first chunk into buf0 (overlaps table packing below).
    {
        int rows0 = min(CHUNK, B - cb * CHUNK);
        int nfl0  = rows0 * 7;
        int nf40  = nfl0 >> 2;
        const float* src = x + (size_t)cb * CHUNK * 7;
        for (int i = tid; i < nf40; i += BLOCK)
            gload16((const float4*)src + i, &buf[0][i * 4]);
        for (int i = (nf40 << 2) + tid; i < nfl0; i += BLOCK)
            gload4(src + i, &buf[0][i]);
    }
    // Narrow table: load f32 from ws (L2-hot), pack (g[i],g[i+1]) as 2xbf16.
    for (int i = tid; i < GPCK / 4; i += BLOCK) {
        float4 q = ((const float4*)g2)[i];
        float ny = g2[i * 4 + 4];
        tn[i*4+0] = bfpack(q.x, q.y); tn[i*4+1] = bfpack(q.y, q.z);
        tn[i*4+2] = bfpack(q.z, q.w); tn[i*4+3] = bfpack(q.w, ny);
    }
    __syncthreads();   // table ready + buf0 DMA drained (vmcnt(0) in barrier)

    int cur = 0;
    for (int c = cb; c < ce; ++c) {
        // Issue next chunk's staging DMA (hides under this chunk's compute).
        if (c + 1 < ce) {
            int rowsN = min(CHUNK, B - (c + 1) * CHUNK);
            int nflN  = rowsN * 7;
            int nf4N  = nflN >> 2;
            const float* src = x + (size_t)(c + 1) * CHUNK * 7;
            for (int i = tid; i < nf4N; i += BLOCK)
                gload16((const float4*)src + i, &buf[cur ^ 1][i * 4]);
            for (int i = (nf4N << 2) + tid; i < nflN; i += BLOCK)
                gload4(src + i, &buf[cur ^ 1][i]);
        }

        int rows = min(CHUNK, B - c * CHUNK);
        float* bfr = buf[cur];
        for (int r = tid; r < rows; r += BLOCK) {
            float* row = bfr + r * 7;                 // stride 7 dwords: 2/bank, free
            float x0 = row[0], x2 = row[2], x6 = row[6];
            float f = (x6 <= 0.f) ? (x6 + 1.f) : (1.f - x6);   // loop constant
            // step 1: wide table, gathered from global (L2-resident, f32 lerp)
            {
                float p = fmaf(x2, f * IHW_, CW_);
                p = fminf(fmaxf(p, 0.f), (float)NW);
                int idx = (int)p; float fr = p - (float)idx;
                float e0 = g1[idx], e1 = g1[idx + 1];
                x2 = fmaf(e1 - e0, fr, e0);
            }
            float af2 = f * IH2;
            // steps 2..9: narrow LDS table (packed bf16 pair, one ds_read_b32)
#pragma unroll
            for (int s = 0; s < 8; ++s) {
                float p = fmaf(x2, af2, C2);
                p = fminf(fmaxf(p, 0.f), (float)N2);
                int idx = (int)p; float fr = p - (float)idx;
                x2 = lerp_pk(tn[idx], fr);
            }
            // step 10 + outputs (x3/x4/x5 survive only from last step)
            float t = x2 * f;
            float p = fmaf(t, IH2, C2);
            p = fminf(fmaxf(p, 0.f), (float)N2);
            int idx = (int)p; float fr = p - (float)idx;
            float x2f = lerp_pk(tn[idx], fr);
            float x4 = t + LAT_CONST;
            row[0] = x0 + 10.f;            // 10 steps of +1
            row[2] = x2f;
            row[3] = x4 * GRAD_CONST;
            row[4] = x4;
            row[5] = t * SEND_CONST;       // row[1], row[6] pass through
        }
        __syncthreads();   // results visible; next-chunk DMA also drained

        // Store chunk: LDS -> global, dense float4 + scalar remainder.
        {
            int nfl = rows * 7;
            int nf4 = nfl >> 2;
            float* dst = out + (size_t)c * CHUNK * 7;
            const float4* s4 = (const float4*)bfr;
            for (int i = tid; i < nf4; i += BLOCK) ((float4*)dst)[i] = s4[i];
            for (int i = (nf4 << 2) + tid; i < nfl; i += BLOCK) dst[i] = bfr[i];
        }
        __syncthreads();   // store-phase ds_reads done before bfr is re-staged
        cur ^= 1;
    }
}

static inline size_t align16h(size_t v) { return (v + 15) & ~(size_t)15; }

extern "C" void kernel_launch(void* const* d_in, const int* in_sizes, int n_in,
                              void* d_out, int out_size, void* d_ws, size_t ws_size,
                              hipStream_t stream)
{
    const float* x  = (const float*)d_in[0];
    const float* W1 = (const float*)d_in[1];
    const float* b1 = (const float*)d_in[2];
    const float* W2 = (const float*)d_in[3];
    const float* b2 = (const float*)d_in[4];
    const float* W3 = (const float*)d_in[5];
    const float* b3 = (const float*)d_in[6];
    float* out = (float*)d_out;

    int B = in_sizes[0] / 7;

    // ws layout: [g1 (GSZ) f32][g2 (GSZ) f32]
    char* ws = (char*)d_ws;
    float* g1 = (float*)ws;
    float* g2 = (float*)(ws + align16h((size_t)GSZ * 4));

    int nChunks = (B + CHUNK - 1) / CHUNK;
    int grid    = (nChunks < MAXBLK) ? nChunks : MAXBLK;

    hipLaunchKernelGGL(build_table_kernel, dim3((2 * GSZ) / 64), dim3(256), 0, stream,
                       W1, b1, W2, b2, W3, b3, g1, g2);
    hipLaunchKernelGGL(rows_kernel, dim3(grid), dim3(BLOCK), 0, stream,
                       x, g1, g2, out, B, nChunks, grid);
}